// Round 2
// baseline (21579.781 us; speedup 1.0000x reference)
//
#include <hip/hip_runtime.h>
#include <hip/hip_bf16.h>
#include <stdint.h>

// ---------------- threefry2x32 (bit-exact vs JAX) ----------------
__device__ __forceinline__ uint32_t rotl32(uint32_t v, int r) {
    return (v << r) | (v >> (32 - r));
}

__device__ __forceinline__ void threefry2x32(uint32_t k0, uint32_t k1,
                                             uint32_t x0, uint32_t x1,
                                             uint32_t& o0, uint32_t& o1) {
    const uint32_t k2 = k0 ^ k1 ^ 0x1BD11BDAu;
    x0 += k0; x1 += k1;
#define TF_RND(r) { x0 += x1; x1 = rotl32(x1, r); x1 ^= x0; }
    TF_RND(13) TF_RND(15) TF_RND(26) TF_RND(6)
    x0 += k1; x1 += k2 + 1u;
    TF_RND(17) TF_RND(29) TF_RND(16) TF_RND(24)
    x0 += k2; x1 += k0 + 2u;
    TF_RND(13) TF_RND(15) TF_RND(26) TF_RND(6)
    x0 += k0; x1 += k1 + 3u;
    TF_RND(17) TF_RND(29) TF_RND(16) TF_RND(24)
    x0 += k1; x1 += k2 + 4u;
    TF_RND(13) TF_RND(15) TF_RND(26) TF_RND(6)
    x0 += k2; x1 += k0 + 5u;
#undef TF_RND
    o0 = x0; o1 = x1;
}

// ---------------- generic fp32 tiled GEMM ----------------
// C[M,N] = A[M,K] @ op(B) + bias.  TRANSB: B is [N,K] (torch weight). else B is [K,N].
constexpr int BM = 64, BN = 32, BK = 16;

template<bool TRANSB, bool ATOMIC>
__device__ __forceinline__ void gemm_tile(
    float* As, float* Bs,
    const float* __restrict__ A, long long lda,
    const float* __restrict__ B, int ldb,
    const float* __restrict__ bias,
    float* __restrict__ C, int ldc,
    int m0, int n0, int kbase, int ksize)
{
    const int tid = threadIdx.x;          // 256 threads
    const int tx = tid & 15;              // n: 2 each -> 32
    const int ty = tid >> 4;              // m: 4 each -> 64
    float acc[4][2] = {{0.f,0.f},{0.f,0.f},{0.f,0.f},{0.f,0.f}};
    const int arow = tid >> 2;            // 0..63
    const int ak   = (tid & 3) << 2;      // 0,4,8,12

    for (int k0 = kbase; k0 < kbase + ksize; k0 += BK) {
        // A tile: As[k][m]
        const float4 av = *(const float4*)(A + (long long)(m0 + arow) * lda + (k0 + ak));
        As[(ak+0)*BM + arow] = av.x;
        As[(ak+1)*BM + arow] = av.y;
        As[(ak+2)*BM + arow] = av.z;
        As[(ak+3)*BM + arow] = av.w;
        if (TRANSB) {
            if (tid < 128) {
                const int brow = tid >> 2;        // 0..31
                const int bk   = (tid & 3) << 2;
                const float4 bv = *(const float4*)(B + (long long)(n0 + brow) * ldb + (k0 + bk));
                Bs[(bk+0)*BN + brow] = bv.x;
                Bs[(bk+1)*BN + brow] = bv.y;
                Bs[(bk+2)*BN + brow] = bv.z;
                Bs[(bk+3)*BN + brow] = bv.w;
            }
        } else {
            if (tid < 128) {
                const int bk = tid >> 3;          // 0..15
                const int bn = (tid & 7) << 2;    // 0..28
                const float4 bv = *(const float4*)(B + (long long)(k0 + bk) * ldb + (n0 + bn));
                *(float4*)(Bs + bk*BN + bn) = bv;
            }
        }
        __syncthreads();
#pragma unroll
        for (int kk = 0; kk < BK; ++kk) {
            const float a0 = As[kk*BM + ty*4+0];
            const float a1 = As[kk*BM + ty*4+1];
            const float a2 = As[kk*BM + ty*4+2];
            const float a3 = As[kk*BM + ty*4+3];
            const float b0 = Bs[kk*BN + tx*2+0];
            const float b1 = Bs[kk*BN + tx*2+1];
            acc[0][0] += a0*b0; acc[0][1] += a0*b1;
            acc[1][0] += a1*b0; acc[1][1] += a1*b1;
            acc[2][0] += a2*b0; acc[2][1] += a2*b1;
            acc[3][0] += a3*b0; acc[3][1] += a3*b1;
        }
        __syncthreads();
    }
#pragma unroll
    for (int i = 0; i < 4; ++i) {
        const int m = m0 + ty*4 + i;
#pragma unroll
        for (int j = 0; j < 2; ++j) {
            const int n = n0 + tx*2 + j;
            if (ATOMIC) {
                atomicAdd(&C[(long long)m*ldc + n], acc[i][j]);
            } else {
                float v = acc[i][j];
                if (bias) v += bias[n];
                C[(long long)m*ldc + n] = v;
            }
        }
    }
}

__global__ __launch_bounds__(256) void k_gemm_abT(
    const float* __restrict__ A, long long lda,
    const float* __restrict__ B,
    const float* __restrict__ bias,
    float* __restrict__ C, int N, int K)
{
    __shared__ float As[BK*BM];
    __shared__ float Bs[BK*BN];
    gemm_tile<true,false>(As, Bs, A, lda, B, K, bias, C, N,
                          blockIdx.y*BM, blockIdx.x*BN, 0, K);
}

// gi = x @ W_ih^T + b_ih  (K=256) ; gh = h @ W_hh^T + b_hh (K=1024)
__global__ __launch_bounds__(256) void k_gru_gemms(
    const float* __restrict__ x, const float* __restrict__ h,
    const float* __restrict__ W_ih, const float* __restrict__ W_hh,
    const float* __restrict__ b_ih, const float* __restrict__ b_hh,
    float* __restrict__ gi, float* __restrict__ gh)
{
    __shared__ float As[BK*BM];
    __shared__ float Bs[BK*BN];
    if (blockIdx.z == 0)
        gemm_tile<true,false>(As, Bs, x, 256, W_ih, 256, b_ih, gi, 3072,
                              blockIdx.y*BM, blockIdx.x*BN, 0, 256);
    else
        gemm_tile<true,false>(As, Bs, h, 1024, W_hh, 1024, b_hh, gh, 3072,
                              blockIdx.y*BM, blockIdx.x*BN, 0, 1024);
}

// x += Y @ E  (Y: [128,8192] strided rows in d_out; E: [8192,256]) split-K atomic
__global__ __launch_bounds__(256) void k_embed(
    const float* __restrict__ Y, const float* __restrict__ E,
    float* __restrict__ X)
{
    __shared__ float As[BK*BM];
    __shared__ float Bs[BK*BN];
    gemm_tile<false,true>(As, Bs, Y, 128LL*8192LL, E, 256, nullptr, X, 256,
                          blockIdx.y*BM, blockIdx.x*BN, blockIdx.z*512, 512);
}

__global__ void k_zero(float* __restrict__ x) {
    x[blockIdx.x*256 + threadIdx.x] = 0.f;
}

// GRU gate nonlinearity: h = (1-z)*n + z*h
__global__ __launch_bounds__(256) void k_gates(
    const float* __restrict__ gi, const float* __restrict__ gh,
    float* __restrict__ h)
{
    const int idx = blockIdx.x*256 + threadIdx.x;   // < 128*1024
    const int b = idx >> 10, i = idx & 1023;
    const float* gib = gi + b*3072;
    const float* ghb = gh + b*3072;
    const float r = 1.f/(1.f + expf(-(gib[i]        + ghb[i])));
    const float z = 1.f/(1.f + expf(-(gib[i+1024]   + ghb[i+1024])));
    const float n = tanhf(gib[i+2048] + r*ghb[i+2048]);
    h[idx] = (1.f - z)*n + z*h[idx];
}

// ---------------- gumbel + softmax (one block per batch row) ----------------
__device__ __forceinline__ float wred_max(float v) {
#pragma unroll
    for (int off = 32; off > 0; off >>= 1)
        v = fmaxf(v, __shfl_down(v, off, 64));
    return v;
}
__device__ __forceinline__ float wred_sum(float v) {
#pragma unroll
    for (int off = 32; off > 0; off >>= 1)
        v += __shfl_down(v, off, 64);
    return v;
}

__global__ __launch_bounds__(1024) void k_sample(
    const float* __restrict__ logits, const float* __restrict__ temp,
    float* __restrict__ out, float* __restrict__ x, int t)
{
    const int b = blockIdx.x;
    const int tid = threadIdx.x;

    // zero x for next step's embed accumulation
    const int gid = b*1024 + tid;
    if (gid < 128*256) x[gid] = 0.f;

    // key_t = threefry((0,42),(0,t))   [jax fold_in semantics]
    uint32_t k0t, k1t;
    threefry2x32(0u, 42u, 0u, (uint32_t)t, k0t, k1t);

    const float tau = temp[0];
    float s[8];
    float m = -3.4e38f;
#pragma unroll
    for (int j = 0; j < 8; ++j) {
        const int v = tid + j*1024;
        const float lg = logits[b*8192 + v];
        // jax_threefry_partitionable=True (modern default):
        // element flat-index i (uint64) -> threefry(key_t, (hi32(i), lo32(i)));
        // 32-bit bits = out0 ^ out1.  Here i = b*8192+v < 2^20 so hi32 = 0.
        const uint32_t idx = (uint32_t)(b*8192 + v);
        uint32_t o0, o1;
        threefry2x32(k0t, k1t, 0u, idx, o0, o1);
        const uint32_t bits = o0 ^ o1;
        float f = __uint_as_float((bits >> 9) | 0x3f800000u) - 1.0f;
        if (f == 0.0f) f = 1.17549435e-38f;           // uniform minval = tiny
        const float g = -logf(-logf(f));
        s[j] = (lg + g) / tau;
        m = fmaxf(m, s[j]);
    }

    __shared__ float red[16];
    const int lane = tid & 63, wid = tid >> 6;

    float wm = wred_max(m);
    if (lane == 0) red[wid] = wm;
    __syncthreads();
    if (tid < 64) {
        float v = (tid < 16) ? red[tid] : -3.4e38f;
        v = wred_max(v);
        if (tid == 0) red[0] = v;
    }
    __syncthreads();
    m = red[0];
    __syncthreads();

    float e[8];
    float sum = 0.f;
#pragma unroll
    for (int j = 0; j < 8; ++j) {
        e[j] = expf(s[j] - m);
        sum += e[j];
    }
    float ws_ = wred_sum(sum);
    if (lane == 0) red[wid] = ws_;
    __syncthreads();
    if (tid < 64) {
        float v = (tid < 16) ? red[tid] : 0.f;
        v = wred_sum(v);
        if (tid == 0) red[0] = v;
    }
    __syncthreads();
    const float inv = 1.0f / red[0];

    const size_t obase = ((size_t)b*128 + (size_t)t)*8192;
#pragma unroll
    for (int j = 0; j < 8; ++j)
        out[obase + tid + j*1024] = e[j]*inv;
}

// ---------------- launch ----------------
extern "C" void kernel_launch(void* const* d_in, const int* in_sizes, int n_in,
                              void* d_out, int out_size, void* d_ws, size_t ws_size,
                              hipStream_t stream) {
    (void)in_sizes; (void)n_in; (void)out_size; (void)ws_size;
    const float* noise  = (const float*)d_in[0];
    const float* temp   = (const float*)d_in[1];
    const float* W_init = (const float*)d_in[2];
    const float* b_init = (const float*)d_in[3];
    const float* E      = (const float*)d_in[4];
    const float* W_ih   = (const float*)d_in[5];
    const float* W_hh   = (const float*)d_in[6];
    const float* b_ih   = (const float*)d_in[7];
    const float* b_hh   = (const float*)d_in[8];
    const float* W_out  = (const float*)d_in[9];
    const float* b_out  = (const float*)d_in[10];
    float* out = (float*)d_out;

    float* ws     = (float*)d_ws;
    float* h      = ws;                 // 128*1024
    float* x      = h  + 131072;        // 128*256
    float* gi     = x  + 32768;         // 128*3072
    float* gh     = gi + 393216;        // 128*3072
    float* logits = gh + 393216;        // 128*8192

    // x = 0 (x_0 = onehot(pad) @ E = E[0] = 0)
    k_zero<<<dim3(128), dim3(256), 0, stream>>>(x);
    // h0 = noise @ W_init^T + b_init   (M=128,N=1024,K=128)
    k_gemm_abT<<<dim3(1024/BN, 2), dim3(256), 0, stream>>>(
        noise, 128LL, W_init, b_init, h, 1024, 128);

    for (int t = 0; t < 128; ++t) {
        if (t > 0) {
            // x = y_{t-1} @ E  (rows of d_out at (b, t-1, :), row stride 128*8192)
            k_embed<<<dim3(256/BN, 2, 16), dim3(256), 0, stream>>>(
                out + (size_t)(t-1)*8192, E, x);
        }
        k_gru_gemms<<<dim3(3072/BN, 2, 2), dim3(256), 0, stream>>>(
            x, h, W_ih, W_hh, b_ih, b_hh, gi, gh);
        k_gates<<<dim3(512), dim3(256), 0, stream>>>(gi, gh, h);
        // logits = h @ W_out^T + b_out  (M=128,N=8192,K=1024)
        k_gemm_abT<<<dim3(8192/BN, 2), dim3(256), 0, stream>>>(
            h, 1024LL, W_out, b_out, logits, 8192, 1024);
        // gumbel + softmax -> y_t, also zeroes x for next step
        k_sample<<<dim3(128), dim3(1024), 0, stream>>>(logits, temp, out, x, t);
    }
}